// Round 9
// baseline (1122.119 us; speedup 1.0000x reference)
//
#include <hip/hip_runtime.h>
#include <hip/hip_bf16.h>
#include <math.h>

#define N_EDGESC  1048576
#define N_GRAPHSC 8192
#define NPG 32     // nodes per graph
#define EPG 128    // edges per graph
#define FXD 78
#define F2C 156
#define F3C 312
#define GHC 156    // Wg1 out
#define GOC 128    // Wg2 out
#define HS  36     // As fp32 row stride
#define XBS 40     // Xb bf16 row stride (80 B: bank step 20 -> conflict-free)
#define HBS 168    // Hb row stride in shorts (84 dwords; m*84%32 cycles banks)
#define RBK 8      // rows per block in cell/ghead kernels
#define NCELLB (N_GRAPHSC / RBK)   // 1024 cell blocks lead the fused grid

typedef __attribute__((ext_vector_type(8))) short short8v;   // 8 bf16 = 4 VGPR
typedef __attribute__((ext_vector_type(4))) short short4v;
typedef __attribute__((ext_vector_type(4))) float float4v;

__device__ __forceinline__ short f2bf(float x) {  // RNE truncate f32->bf16 bits
  unsigned u = __float_as_uint(x);
  u += 0x7FFFu + ((u >> 16) & 1u);
  return (short)(u >> 16);
}

// ---------------------------------------------------------------------------
// MFMA aggregation: Hb[s][f] = bf16( sum_d A[s][d] * H[d][f] ).
template<int NT>
__device__ __forceinline__ void agg_mfma(const short* __restrict__ Asb,
                                         const short* __restrict__ Xb,
                                         short* __restrict__ Hb, int t) {
  const int w = t >> 6;
  const int L = t & 63;
  const int q = L >> 4;
  const int mt = w & 1;
  const int m = mt * 16 + (L & 15);
  const short8v afrag = *(const short8v*)(Asb + m * 32 + q * 8);
  for (int nt = (w >> 1); nt < NT; nt += 2) {
    const int f = nt * 16 + (L & 15);
    const short8v bfrag = *(const short8v*)(Xb + f * XBS + q * 8);
    float4v acc = {0.f, 0.f, 0.f, 0.f};
    acc = __builtin_amdgcn_mfma_f32_16x16x32_bf16(afrag, bfrag, acc, 0, 0, 0);
#pragma unroll
    for (int i = 0; i < 4; ++i)
      Hb[(mt * 16 + q * 4 + i) * HBS + f] = f2bf(acc[i]);   // f < 160 < HBS
  }
}

// ---------------------------------------------------------------------------
// MFMA mm: D[m][f] = sum_k Hb[m][k] * Wt[f][k] (+bias, relu).
template<int KSTEPS, int NT, int KP, int FOUT, bool POOL>
__device__ __forceinline__ void mm_mfma(const short* __restrict__ Hb,
                                        const short* __restrict__ Wt,
                                        const float* __restrict__ bias,
                                        short* __restrict__ Xout,
                                        unsigned* __restrict__ gmax, int t) {
  const int w = t >> 6;
  const int L = t & 63;
  const int q = L >> 4;
  const int mt = w & 1;                 // wave -> fixed m-tile (A-frag reuse)
  const int m = mt * 16 + (L & 15);
  short8v afrag[KSTEPS];
#pragma unroll
  for (int s = 0; s < KSTEPS; ++s)
    afrag[s] = *(const short8v*)(Hb + m * HBS + s * 32 + q * 8);
  for (int nt = (w >> 1); nt < NT; nt += 2) {
    const int f = nt * 16 + (L & 15);
    float4v acc = {0.f, 0.f, 0.f, 0.f};
#pragma unroll
    for (int s = 0; s < KSTEPS; ++s) {
      short8v bfrag = *(const short8v*)(Wt + (size_t)f * KP + s * 32 + q * 8);
      acc = __builtin_amdgcn_mfma_f32_16x16x32_bf16(afrag[s], bfrag, acc, 0, 0, 0);
    }
    if (f < FOUT) {
      float bb = bias[f];
      float o0 = fmaxf(acc[0] + bb, 0.f), o1 = fmaxf(acc[1] + bb, 0.f);
      float o2 = fmaxf(acc[2] + bb, 0.f), o3 = fmaxf(acc[3] + bb, 0.f);
      if constexpr (POOL) {
        float mx = fmaxf(fmaxf(o0, o1), fmaxf(o2, o3));
        atomicMax(&gmax[f], __float_as_uint(mx));   // relu'd >= 0 -> monotone
      } else {
        short4v o4;
        o4[0] = f2bf(o0); o4[1] = f2bf(o1); o4[2] = f2bf(o2); o4[3] = f2bf(o3);
        *(short4v*)(Xout + (size_t)f * XBS + mt * 16 + q * 4) = o4;
      }
    }
  }
}

// ---------------------------------------------------------------------------
// Weight pre-pack: Wt[f][k] = bf16(W[k][f]), zero-padded to Np x Kp.
__global__ __launch_bounds__(256)
void pack_wt(const float* __restrict__ src, short* __restrict__ dst,
             int FIN, int FOUT, int Kp, int Np) {
  int idx = blockIdx.x * 256 + threadIdx.x;
  if (idx >= Np * Kp) return;
  int f = idx / Kp, k = idx - f * Kp;
  float v = (f < FOUT && k < FIN) ? src[(size_t)k * FOUT + f] : 0.f;
  dst[idx] = f2bf(v);
}

// ---------------------------------------------------------------------------
// Fused kernel (R8-proven): blocks [0,1024) = cell MLP; rest = drug GCN.
__global__ __launch_bounds__(256, 3)
void fused_kernel(const float* __restrict__ x1, const int* __restrict__ ei1,
                  const float* __restrict__ x2, const int* __restrict__ ei2,
                  const short* __restrict__ Wt1, const float* __restrict__ b1,
                  const short* __restrict__ Wt2, const float* __restrict__ b2,
                  const short* __restrict__ Wt3, const float* __restrict__ b3,
                  float* __restrict__ pbuf,
                  const float* __restrict__ cell,
                  const float* __restrict__ Wr1, const float* __restrict__ br1,
                  const float* __restrict__ Wr2, const float* __restrict__ br2,
                  const float* __restrict__ Wr3, const float* __restrict__ br3,
                  float* __restrict__ cout) {
  __shared__ __align__(16) char smem[31584];
  const int t = threadIdx.x;

  if (blockIdx.x < NCELLB) {
    float* U  = (float*)smem;             // 16384 B
    float* h2 = (float*)(smem + 16384);   //  8192 B
    const int R = blockIdx.x * RBK;
    const int r0 = (t & 1) * 4;
    const int f = t >> 1;

    float acc[4][4];
#pragma unroll
    for (int i = 0; i < 4; ++i)
#pragma unroll
      for (int j = 0; j < 4; ++j) acc[i][j] = 0.f;

    const int ra = t / 50, ka = t - ra * 50;
    const int i2 = t + 256;
    const int rb = i2 / 50, kb = i2 - rb * 50;
    float4 va, vb;
    va = *(const float4*)(cell + (size_t)(R + ra) * 1000 + ka * 4);
    if (t < 144) vb = *(const float4*)(cell + (size_t)(R + rb) * 1000 + kb * 4);

    for (int k0 = 0; k0 < 1000; k0 += 200) {
      __syncthreads();
      {
        int kk = ka * 4;
        U[(kk + 0) * RBK + ra] = va.x; U[(kk + 1) * RBK + ra] = va.y;
        U[(kk + 2) * RBK + ra] = va.z; U[(kk + 3) * RBK + ra] = va.w;
        if (t < 144) {
          int kk2 = kb * 4;
          U[(kk2 + 0) * RBK + rb] = vb.x; U[(kk2 + 1) * RBK + rb] = vb.y;
          U[(kk2 + 2) * RBK + rb] = vb.z; U[(kk2 + 3) * RBK + rb] = vb.w;
        }
      }
      if (k0 + 200 < 1000) {
        va = *(const float4*)(cell + (size_t)(R + ra) * 1000 + (k0 + 200) + ka * 4);
        if (t < 144)
          vb = *(const float4*)(cell + (size_t)(R + rb) * 1000 + (k0 + 200) + kb * 4);
      }
      __syncthreads();
#pragma unroll 8
      for (int k = 0; k < 200; ++k) {
        float4 h = *(const float4*)(U + k * RBK + r0);
        const float* wr = Wr1 + (size_t)(k0 + k) * 512 + f;
#pragma unroll
        for (int j = 0; j < 4; ++j) {
          float w = wr[j * 128];
          acc[0][j] = fmaf(h.x, w, acc[0][j]);
          acc[1][j] = fmaf(h.y, w, acc[1][j]);
          acc[2][j] = fmaf(h.z, w, acc[2][j]);
          acc[3][j] = fmaf(h.w, w, acc[3][j]);
        }
      }
    }
    __syncthreads();
#pragma unroll
    for (int j = 0; j < 4; ++j) {
      int ff = f + j * 128;
      float bb = br1[ff];
      float4 o;
      o.x = fmaxf(acc[0][j] + bb, 0.f); o.y = fmaxf(acc[1][j] + bb, 0.f);
      o.z = fmaxf(acc[2][j] + bb, 0.f); o.w = fmaxf(acc[3][j] + bb, 0.f);
      *(float4*)(U + ff * RBK + r0) = o;
    }
    __syncthreads();

    float a2[4][2];
#pragma unroll
    for (int i = 0; i < 4; ++i) { a2[i][0] = 0.f; a2[i][1] = 0.f; }
#pragma unroll 8
    for (int k = 0; k < 512; ++k) {
      float4 h = *(const float4*)(U + k * RBK + r0);
      const float* wr = Wr2 + (size_t)k * 256 + f;
#pragma unroll
      for (int j = 0; j < 2; ++j) {
        float w = wr[j * 128];
        a2[0][j] = fmaf(h.x, w, a2[0][j]);
        a2[1][j] = fmaf(h.y, w, a2[1][j]);
        a2[2][j] = fmaf(h.z, w, a2[2][j]);
        a2[3][j] = fmaf(h.w, w, a2[3][j]);
      }
    }
#pragma unroll
    for (int j = 0; j < 2; ++j) {
      int ff = f + j * 128;
      float bb = br2[ff];
      float4 o;
      o.x = fmaxf(a2[0][j] + bb, 0.f); o.y = fmaxf(a2[1][j] + bb, 0.f);
      o.z = fmaxf(a2[2][j] + bb, 0.f); o.w = fmaxf(a2[3][j] + bb, 0.f);
      *(float4*)(h2 + ff * RBK + r0) = o;
    }
    __syncthreads();

    float a3[4];
#pragma unroll
    for (int i = 0; i < 4; ++i) a3[i] = 0.f;
#pragma unroll 8
    for (int k = 0; k < 256; ++k) {
      float4 h = *(const float4*)(h2 + k * RBK + r0);
      float w = Wr3[(size_t)k * 128 + f];
      a3[0] = fmaf(h.x, w, a3[0]);
      a3[1] = fmaf(h.y, w, a3[1]);
      a3[2] = fmaf(h.z, w, a3[2]);
      a3[3] = fmaf(h.w, w, a3[3]);
    }
    {
      float bb = br3[f];
#pragma unroll
      for (int i = 0; i < 4; ++i)
        cout[(size_t)(R + r0 + i) * GOC + f] = a3[i] + bb;
    }
    return;
  }

  // ================= drug path =================
  short* Xb   = (short*)smem;             // [160][XBS] bf16, 12800 B
  short* Hb   = (short*)(smem + 12800);   // [32][HBS]  bf16, 10752 B
  float* As   = (float*)(smem + 23552);   // [32][HS]   fp32,  4608 B
  short* Asb  = (short*)(smem + 28160);   // [32][32]   bf16,  2048 B
  float* gbuf = (float*)(smem + 30208);   //                   1248 B
  float* deg  = (float*)(smem + 31456);   //                    128 B
  unsigned* gbufU = (unsigned*)gbuf;

  const int bid = blockIdx.x - NCELLB;
  const int gid = bid & (N_GRAPHSC - 1);
  const int drug = bid >> 13;
  const float* __restrict__ x = drug ? x2 : x1;
  const int* __restrict__ ei = drug ? ei2 : ei1;
  const int nbase = gid * NPG;

  if (t < NPG) deg[t] = 0.f;
  for (int i = t; i < NPG * HS; i += 256) As[i] = 0.f;
  for (int i = t; i < NPG * HBS / 2; i += 256) ((int*)Hb)[i] = 0;
  {
    int* xz = (int*)(Xb + FXD * XBS);     // rows [78,160) must stay zero
    for (int i = t; i < (160 - FXD) * XBS / 2; i += 256) xz[i] = 0;
  }
  for (int i = t; i < F3C; i += 256) gbufU[i] = 0u;
  const float* xg = x + (size_t)gid * (NPG * FXD);
  float4 xv[3];
#pragma unroll
  for (int j = 0; j < 3; ++j) {
    int idx = t + j * 256;
    if (idx < (NPG * FXD) / 4) xv[j] = ((const float4*)xg)[idx];
  }
  int s = 0, d = 0;
  if (t < EPG) {
    s = ei[(size_t)gid * EPG + t] - nbase;
    d = ei[(size_t)N_EDGESC + (size_t)gid * EPG + t] - nbase;
  }
#pragma unroll
  for (int j = 0; j < 3; ++j) {
    int idx = t + j * 256;
    if (idx < (NPG * FXD) / 4) {
      const float* vp = (const float*)&xv[j];
      int base = idx * 4;
#pragma unroll
      for (int jj = 0; jj < 4; ++jj) {
        int id2 = base + jj;
        int n = id2 / FXD;
        int k = id2 - n * FXD;
        Xb[k * XBS + n] = f2bf(vp[jj]);
      }
    }
  }
  __syncthreads();
  if (t < EPG) atomicAdd(&deg[s], 1.0f);
  __syncthreads();
  if (t < EPG) {
    float wgt = rsqrtf(deg[s] + 1.0f) * rsqrtf(deg[d] + 1.0f);
    atomicAdd(&As[d * HS + s], wgt);   // A[s][d]: msg d->s
  }
  if (t < NPG) atomicAdd(&As[t * HS + t], 1.0f / (deg[t] + 1.0f));
  __syncthreads();
  for (int i = t; i < NPG * NPG; i += 256) {
    int ss = i >> 5, dd = i & 31;
    Asb[ss * 32 + dd] = f2bf(As[dd * HS + ss]);
  }
  __syncthreads();

  agg_mfma<5>(Asb, Xb, Hb, t);
  __syncthreads();
  mm_mfma<3, 5, 96, FXD, false>(Hb, Wt1, b1, Xb, nullptr, t);
  __syncthreads();
  agg_mfma<5>(Asb, Xb, Hb, t);
  __syncthreads();
  mm_mfma<3, 10, 96, F2C, false>(Hb, Wt2, b2, Xb, nullptr, t);
  __syncthreads();
  agg_mfma<10>(Asb, Xb, Hb, t);
  __syncthreads();
  mm_mfma<5, 20, 160, F3C, true>(Hb, Wt3, b3, nullptr, gbufU, t);
  __syncthreads();

  const int p = drug * N_GRAPHSC + gid;
  for (int i = t; i < F3C; i += 256) pbuf[(size_t)p * F3C + i] = gbuf[i];
}

// ---------------------------------------------------------------------------
// ghead: fused graph-MLP + head. 1024 blocks x 8 samples. All intermediates
// (g1, g2) stay in LDS; no HBM round-trip, no separate gmlp launch.
// LDS overlay (33824 B total -> 4 blocks/CU):
//   phase A: U0[312][8]@0, U1@9984 (pbuf rows)         ends 19968
//   phase B: H1a[156][8]@19968, H1b@24960              ends 29952
//   phase C: g0[128][8]@0, g1v@4096, Uc@8192 (U0/U1 dead)
//   phase D: Uh[512][8]@12288 (H1a/b dead)             ends 28672
//   phase E: h2[128][8]@28672, red@32768, scal@33792
__global__ __launch_bounds__(256, 4)
void ghead_kernel(const float* __restrict__ pbuf, const float* __restrict__ cbuf,
                  const float* __restrict__ Wg1, const float* __restrict__ bg1,
                  const float* __restrict__ Wg2, const float* __restrict__ bg2,
                  const float* __restrict__ Wf1, const float* __restrict__ bf1,
                  const float* __restrict__ Wf2, const float* __restrict__ bf2,
                  const float* __restrict__ Wo, const float* __restrict__ bo,
                  const float* __restrict__ pa, float* __restrict__ out) {
  __shared__ __align__(16) char smem[33824];
  float* U0   = (float*)smem;
  float* U1   = (float*)(smem + 9984);
  float* H1a  = (float*)(smem + 19968);
  float* H1b  = (float*)(smem + 24960);
  float* g0   = (float*)smem;
  float* g1v  = (float*)(smem + 4096);
  float* Uc   = (float*)(smem + 8192);
  float* Uh   = (float*)(smem + 12288);
  float* h2   = (float*)(smem + 28672);
  float* red  = (float*)(smem + 32768);
  float* scal = (float*)(smem + 33792);

  const int t = threadIdx.x;
  const int R = blockIdx.x * RBK;
  const float a = pa[0];
  const int r0 = (t & 1) * 4;
  const int f = t >> 1;                 // 0..127

  // ---- P1: stage pbuf rows for both drugs, [k][r] stride 8
  for (int i = t; i < 2 * 624; i += 256) {
    int dsel = i >= 624, ii = i - dsel * 624;
    int r = ii / 78, c4 = ii - r * 78;
    float4 v = *(const float4*)(pbuf +
        ((size_t)(dsel * N_GRAPHSC + R + r)) * F3C + c4 * 4);
    float* U = dsel ? U1 : U0;
    int k = c4 * 4;
    U[(k + 0) * 8 + r] = v.x; U[(k + 1) * 8 + r] = v.y;
    U[(k + 2) * 8 + r] = v.z; U[(k + 3) * 8 + r] = v.w;
  }
  __syncthreads();

  // ---- P2: gmlp layer 1 (312 -> 156), both drugs
#pragma unroll
  for (int dsel = 0; dsel < 2; ++dsel) {
    const float* U = dsel ? U1 : U0;
    float* H = dsel ? H1b : H1a;
    float acc[4][2];
#pragma unroll
    for (int i = 0; i < 4; ++i) { acc[i][0] = 0.f; acc[i][1] = 0.f; }
#pragma unroll 4
    for (int k = 0; k < F3C; ++k) {
      float4 h = *(const float4*)(U + k * 8 + r0);
      const float* wr = Wg1 + (size_t)k * GHC + f;
#pragma unroll
      for (int j = 0; j < 2; ++j) {
        if (f + j * 128 < GHC) {
          float w = wr[j * 128];
          acc[0][j] = fmaf(h.x, w, acc[0][j]);
          acc[1][j] = fmaf(h.y, w, acc[1][j]);
          acc[2][j] = fmaf(h.z, w, acc[2][j]);
          acc[3][j] = fmaf(h.w, w, acc[3][j]);
        }
      }
    }
#pragma unroll
    for (int j = 0; j < 2; ++j) {
      int ff = f + j * 128;
      if (ff < GHC) {
        float bb = bg1[ff];
        float4 o;
        o.x = fmaxf(acc[0][j] + bb, 0.f); o.y = fmaxf(acc[1][j] + bb, 0.f);
        o.z = fmaxf(acc[2][j] + bb, 0.f); o.w = fmaxf(acc[3][j] + bb, 0.f);
        *(float4*)(H + ff * 8 + r0) = o;
      }
    }
  }
  __syncthreads();

  // ---- P3: stage cbuf -> Uc; gmlp layer 2 (156 -> 128) -> g0/g1v (LDS only)
  {
    int r = t >> 5, c4 = t & 31;
    float4 v = *(const float4*)(cbuf + (size_t)(R + r) * GOC + c4 * 4);
    int k = c4 * 4;
    Uc[(k + 0) * 8 + r] = v.x; Uc[(k + 1) * 8 + r] = v.y;
    Uc[(k + 2) * 8 + r] = v.z; Uc[(k + 3) * 8 + r] = v.w;
  }
#pragma unroll
  for (int dsel = 0; dsel < 2; ++dsel) {
    const float* H = dsel ? H1b : H1a;
    float* g = dsel ? g1v : g0;
    float a2[4];
#pragma unroll
    for (int i = 0; i < 4; ++i) a2[i] = 0.f;
#pragma unroll 4
    for (int k = 0; k < GHC; ++k) {
      float4 h = *(const float4*)(H + k * 8 + r0);
      float w = Wg2[(size_t)k * GOC + f];
      a2[0] = fmaf(h.x, w, a2[0]);
      a2[1] = fmaf(h.y, w, a2[1]);
      a2[2] = fmaf(h.z, w, a2[2]);
      a2[3] = fmaf(h.w, w, a2[3]);
    }
    {
      float bb = bg2[f];
      float4 o = {a2[0] + bb, a2[1] + bb, a2[2] + bb, a2[3] + bb};
      *(float4*)(g + f * 8 + r0) = o;
    }
  }
  __syncthreads();

  // ---- P4: deterministic ssq -> scal  (32 lanes per row)
  {
    int r = t >> 5, l = t & 31;
    float s2 = 0.f;
#pragma unroll
    for (int j = 0; j < 4; ++j) { float v = g0 [(l + 32 * j) * 8 + r]; s2 = fmaf(v, v, s2); }
#pragma unroll
    for (int j = 0; j < 4; ++j) { float v = g1v[(l + 32 * j) * 8 + r]; s2 = fmaf(v, v, s2); }
#pragma unroll
    for (int j = 0; j < 4; ++j) { float v = Uc [(l + 32 * j) * 8 + r]; s2 = fmaf(v, v, s2); }
    red[t] = s2;
  }
  __syncthreads();
  if (t < RBK) {
    float s2 = 0.f;
#pragma unroll
    for (int i = 0; i < 32; ++i) s2 += red[t * 32 + i];
    scal[t] = 1.0f / fmaxf(sqrtf(s2), 1e-12f);
  }
  __syncthreads();

  // ---- P5: head layer 1 (384 -> 512): k-order 0..383 via 3 sub-loops
  {
    float acc[4][4];
#pragma unroll
    for (int i = 0; i < 4; ++i)
#pragma unroll
      for (int j = 0; j < 4; ++j) acc[i][j] = 0.f;
#pragma unroll 4
    for (int k = 0; k < 128; ++k) {
      float4 h = *(const float4*)(g0 + k * 8 + r0);
      const float* wr = Wf1 + (size_t)k * 512 + f;
#pragma unroll
      for (int j = 0; j < 4; ++j) {
        float w = wr[j * 128];
        acc[0][j] = fmaf(h.x, w, acc[0][j]);
        acc[1][j] = fmaf(h.y, w, acc[1][j]);
        acc[2][j] = fmaf(h.z, w, acc[2][j]);
        acc[3][j] = fmaf(h.w, w, acc[3][j]);
      }
    }
#pragma unroll 4
    for (int k = 0; k < 128; ++k) {
      float4 h = *(const float4*)(g1v + k * 8 + r0);
      const float* wr = Wf1 + (size_t)(k + 128) * 512 + f;
#pragma unroll
      for (int j = 0; j < 4; ++j) {
        float w = wr[j * 128];
        acc[0][j] = fmaf(h.x, w, acc[0][j]);
        acc[1][j] = fmaf(h.y, w, acc[1][j]);
        acc[2][j] = fmaf(h.z, w, acc[2][j]);
        acc[3][j] = fmaf(h.w, w, acc[3][j]);
      }
    }
#pragma unroll 4
    for (int k = 0; k < 128; ++k) {
      float4 h = *(const float4*)(Uc + k * 8 + r0);
      const float* wr = Wf1 + (size_t)(k + 256) * 512 + f;
#pragma unroll
      for (int j = 0; j < 4; ++j) {
        float w = wr[j * 128];
        acc[0][j] = fmaf(h.x, w, acc[0][j]);
        acc[1][j] = fmaf(h.y, w, acc[1][j]);
        acc[2][j] = fmaf(h.z, w, acc[2][j]);
        acc[3][j] = fmaf(h.w, w, acc[3][j]);
      }
    }
    __syncthreads();     // H1a/H1b dead; Uh overlay becomes writable
#pragma unroll
    for (int j = 0; j < 4; ++j) {
      int ff = f + j * 128;
      float bb = bf1[ff];
      float4 o;
      float v0 = acc[0][j] * scal[r0 + 0] + bb; o.x = v0 >= 0.f ? v0 : a * v0;
      float v1 = acc[1][j] * scal[r0 + 1] + bb; o.y = v1 >= 0.f ? v1 : a * v1;
      float v2 = acc[2][j] * scal[r0 + 2] + bb; o.z = v2 >= 0.f ? v2 : a * v2;
      float v3 = acc[3][j] * scal[r0 + 3] + bb; o.w = v3 >= 0.f ? v3 : a * v3;
      *(float4*)(Uh + ff * 8 + r0) = o;
    }
  }
  __syncthreads();

  // ---- P6: head layer 2 (512 -> 128)
  {
    float a2[4];
#pragma unroll
    for (int i = 0; i < 4; ++i) a2[i] = 0.f;
#pragma unroll 8
    for (int k = 0; k < 512; ++k) {
      float4 h = *(const float4*)(Uh + k * 8 + r0);
      float w = Wf2[(size_t)k * 128 + f];
      a2[0] = fmaf(h.x, w, a2[0]);
      a2[1] = fmaf(h.y, w, a2[1]);
      a2[2] = fmaf(h.z, w, a2[2]);
      a2[3] = fmaf(h.w, w, a2[3]);
    }
    float bb = bf2[f];
#pragma unroll
    for (int i = 0; i < 4; ++i) {
      float v = a2[i] + bb;
      v = v >= 0.f ? v : a * v;
      h2[f * 8 + (r0 + i)] = v;
    }
  }
  __syncthreads();

  // ---- P7: Wo dot + sigmoid
  {
    int rr = t >> 5, kp = t & 31;
    float p = 0.f;
#pragma unroll
    for (int jj = 0; jj < 4; ++jj) {
      int k = kp + 32 * jj;
      p = fmaf(h2[k * 8 + rr], Wo[k], p);
    }
    red[t] = p;
  }
  __syncthreads();
  if (t < RBK) {
    float ssum = bo[0];
#pragma unroll
    for (int i = 0; i < 32; ++i) ssum += red[t * 32 + i];
    out[R + t] = 1.0f / (1.0f + expf(-ssum));
  }
}

// ---------------------------------------------------------------------------
extern "C" void kernel_launch(void* const* d_in, const int* in_sizes, int n_in,
                              void* d_out, int out_size, void* d_ws, size_t ws_size,
                              hipStream_t stream) {
  const float* x1  = (const float*)d_in[0];
  const int*   ei1 = (const int*)d_in[1];
  const float* x2  = (const float*)d_in[2];
  const int*   ei2 = (const int*)d_in[3];
  const float* cel = (const float*)d_in[4];
  const float* W1  = (const float*)d_in[7];
  const float* b1  = (const float*)d_in[8];
  const float* W2  = (const float*)d_in[9];
  const float* b2  = (const float*)d_in[10];
  const float* W3  = (const float*)d_in[11];
  const float* b3  = (const float*)d_in[12];
  const float* Wg1 = (const float*)d_in[13];
  const float* bg1 = (const float*)d_in[14];
  const float* Wg2 = (const float*)d_in[15];
  const float* bg2 = (const float*)d_in[16];
  const float* Wr1 = (const float*)d_in[17];
  const float* br1 = (const float*)d_in[18];
  const float* Wr2 = (const float*)d_in[19];
  const float* br2 = (const float*)d_in[20];
  const float* Wr3 = (const float*)d_in[21];
  const float* br3 = (const float*)d_in[22];
  const float* Wf1 = (const float*)d_in[23];
  const float* bf1 = (const float*)d_in[24];
  const float* Wf2 = (const float*)d_in[25];
  const float* bf2 = (const float*)d_in[26];
  const float* Wo  = (const float*)d_in[27];
  const float* bo  = (const float*)d_in[28];
  const float* pa  = (const float*)d_in[29];

  float* ws    = (float*)d_ws;
  float* cbuf  = ws + (size_t)2 * N_GRAPHSC * GOC;
  short* wt1   = (short*)(ws + (size_t)3 * N_GRAPHSC * GOC);  // 80x96
  short* wt2   = wt1 + 80 * 96;                               // 160x96
  short* wt3   = wt2 + 160 * 96;                               // 320x160
  float* pbuf  = ws + (size_t)3 * N_GRAPHSC * GOC + 37120;     // 16384x312
  float* outp  = (float*)d_out;

  pack_wt<<<dim3((80 * 96 + 255) / 256), dim3(256), 0, stream>>>(W1, wt1, FXD, FXD, 96, 80);
  pack_wt<<<dim3((160 * 96 + 255) / 256), dim3(256), 0, stream>>>(W2, wt2, FXD, F2C, 96, 160);
  pack_wt<<<dim3((320 * 160 + 255) / 256), dim3(256), 0, stream>>>(W3, wt3, F2C, F3C, 160, 320);

  fused_kernel<<<dim3(NCELLB + 2 * N_GRAPHSC), dim3(256), 0, stream>>>(
      x1, ei1, x2, ei2, wt1, b1, wt2, b2, wt3, b3, pbuf,
      cel, Wr1, br1, Wr2, br2, Wr3, br3, cbuf);
  ghead_kernel<<<dim3(N_GRAPHSC / RBK), dim3(256), 0, stream>>>(
      pbuf, cbuf, Wg1, bg1, Wg2, bg2, Wf1, bf1, Wf2, bf2, Wo, bo, pa, outp);
}

// Round 10
// 800.672 us; speedup vs baseline: 1.4015x; 1.4015x over previous
//
#include <hip/hip_runtime.h>
#include <hip/hip_bf16.h>
#include <math.h>

#define N_EDGESC  1048576
#define N_GRAPHSC 8192
#define NPG 32     // nodes per graph
#define EPG 128    // edges per graph
#define FXD 78
#define F2C 156
#define F3C 312
#define GHC 156    // Wg1 out
#define GOC 128    // Wg2 out
#define HS  36     // As fp32 row stride
#define XBS 40     // Xb bf16 row stride (80 B: bank step 20 -> conflict-free)
#define HBS 168    // Hb row stride in shorts (84 dwords; m*84%32 cycles banks)
#define RBK 8      // rows per block in cell path
#define GM  16     // samples per block in ghead_mfma (512 blocks)
#define NCELLB (N_GRAPHSC / RBK)   // 1024 cell blocks lead the fused grid

typedef __attribute__((ext_vector_type(8))) short short8v;   // 8 bf16 = 4 VGPR
typedef __attribute__((ext_vector_type(4))) short short4v;
typedef __attribute__((ext_vector_type(4))) float float4v;

__device__ __forceinline__ short f2bf(float x) {  // RNE truncate f32->bf16 bits
  unsigned u = __float_as_uint(x);
  u += 0x7FFFu + ((u >> 16) & 1u);
  return (short)(u >> 16);
}

// ---------------------------------------------------------------------------
// MFMA aggregation: Hb[s][f] = bf16( sum_d A[s][d] * H[d][f] ).
template<int NT>
__device__ __forceinline__ void agg_mfma(const short* __restrict__ Asb,
                                         const short* __restrict__ Xb,
                                         short* __restrict__ Hb, int t) {
  const int w = t >> 6;
  const int L = t & 63;
  const int q = L >> 4;
  const int mt = w & 1;
  const int m = mt * 16 + (L & 15);
  const short8v afrag = *(const short8v*)(Asb + m * 32 + q * 8);
  for (int nt = (w >> 1); nt < NT; nt += 2) {
    const int f = nt * 16 + (L & 15);
    const short8v bfrag = *(const short8v*)(Xb + f * XBS + q * 8);
    float4v acc = {0.f, 0.f, 0.f, 0.f};
    acc = __builtin_amdgcn_mfma_f32_16x16x32_bf16(afrag, bfrag, acc, 0, 0, 0);
#pragma unroll
    for (int i = 0; i < 4; ++i)
      Hb[(mt * 16 + q * 4 + i) * HBS + f] = f2bf(acc[i]);   // f < 160 < HBS
  }
}

// ---------------------------------------------------------------------------
// MFMA mm: D[m][f] = sum_k Hb[m][k] * Wt[f][k] (+bias, relu).
template<int KSTEPS, int NT, int KP, int FOUT, bool POOL>
__device__ __forceinline__ void mm_mfma(const short* __restrict__ Hb,
                                        const short* __restrict__ Wt,
                                        const float* __restrict__ bias,
                                        short* __restrict__ Xout,
                                        unsigned* __restrict__ gmax, int t) {
  const int w = t >> 6;
  const int L = t & 63;
  const int q = L >> 4;
  const int mt = w & 1;                 // wave -> fixed m-tile (A-frag reuse)
  const int m = mt * 16 + (L & 15);
  short8v afrag[KSTEPS];
#pragma unroll
  for (int s = 0; s < KSTEPS; ++s)
    afrag[s] = *(const short8v*)(Hb + m * HBS + s * 32 + q * 8);
  for (int nt = (w >> 1); nt < NT; nt += 2) {
    const int f = nt * 16 + (L & 15);
    float4v acc = {0.f, 0.f, 0.f, 0.f};
#pragma unroll
    for (int s = 0; s < KSTEPS; ++s) {
      short8v bfrag = *(const short8v*)(Wt + (size_t)f * KP + s * 32 + q * 8);
      acc = __builtin_amdgcn_mfma_f32_16x16x32_bf16(afrag[s], bfrag, acc, 0, 0, 0);
    }
    if (f < FOUT) {
      float bb = bias[f];
      float o0 = fmaxf(acc[0] + bb, 0.f), o1 = fmaxf(acc[1] + bb, 0.f);
      float o2 = fmaxf(acc[2] + bb, 0.f), o3 = fmaxf(acc[3] + bb, 0.f);
      if constexpr (POOL) {
        float mx = fmaxf(fmaxf(o0, o1), fmaxf(o2, o3));
        atomicMax(&gmax[f], __float_as_uint(mx));   // relu'd >= 0 -> monotone
      } else {
        short4v o4;
        o4[0] = f2bf(o0); o4[1] = f2bf(o1); o4[2] = f2bf(o2); o4[3] = f2bf(o3);
        *(short4v*)(Xout + (size_t)f * XBS + mt * 16 + q * 4) = o4;
      }
    }
  }
}

// ---------------------------------------------------------------------------
// Weight pre-pack: Wt[f][k] = bf16(W[k][f]), zero-padded to Np x Kp.
__global__ __launch_bounds__(256)
void pack_wt(const float* __restrict__ src, short* __restrict__ dst,
             int FIN, int FOUT, int Kp, int Np) {
  int idx = blockIdx.x * 256 + threadIdx.x;
  if (idx >= Np * Kp) return;
  int f = idx / Kp, k = idx - f * Kp;
  float v = (f < FOUT && k < FIN) ? src[(size_t)k * FOUT + f] : 0.f;
  dst[idx] = f2bf(v);
}

// ---------------------------------------------------------------------------
// Fused kernel (R8-proven, unchanged): blocks [0,1024) = cell MLP; rest = drug.
__global__ __launch_bounds__(256, 3)
void fused_kernel(const float* __restrict__ x1, const int* __restrict__ ei1,
                  const float* __restrict__ x2, const int* __restrict__ ei2,
                  const short* __restrict__ Wt1, const float* __restrict__ b1,
                  const short* __restrict__ Wt2, const float* __restrict__ b2,
                  const short* __restrict__ Wt3, const float* __restrict__ b3,
                  float* __restrict__ pbuf,
                  const float* __restrict__ cell,
                  const float* __restrict__ Wr1, const float* __restrict__ br1,
                  const float* __restrict__ Wr2, const float* __restrict__ br2,
                  const float* __restrict__ Wr3, const float* __restrict__ br3,
                  float* __restrict__ cout) {
  __shared__ __align__(16) char smem[31584];
  const int t = threadIdx.x;

  if (blockIdx.x < NCELLB) {
    float* U  = (float*)smem;             // 16384 B
    float* h2 = (float*)(smem + 16384);   //  8192 B
    const int R = blockIdx.x * RBK;
    const int r0 = (t & 1) * 4;
    const int f = t >> 1;

    float acc[4][4];
#pragma unroll
    for (int i = 0; i < 4; ++i)
#pragma unroll
      for (int j = 0; j < 4; ++j) acc[i][j] = 0.f;

    const int ra = t / 50, ka = t - ra * 50;
    const int i2 = t + 256;
    const int rb = i2 / 50, kb = i2 - rb * 50;
    float4 va, vb;
    va = *(const float4*)(cell + (size_t)(R + ra) * 1000 + ka * 4);
    if (t < 144) vb = *(const float4*)(cell + (size_t)(R + rb) * 1000 + kb * 4);

    for (int k0 = 0; k0 < 1000; k0 += 200) {
      __syncthreads();
      {
        int kk = ka * 4;
        U[(kk + 0) * RBK + ra] = va.x; U[(kk + 1) * RBK + ra] = va.y;
        U[(kk + 2) * RBK + ra] = va.z; U[(kk + 3) * RBK + ra] = va.w;
        if (t < 144) {
          int kk2 = kb * 4;
          U[(kk2 + 0) * RBK + rb] = vb.x; U[(kk2 + 1) * RBK + rb] = vb.y;
          U[(kk2 + 2) * RBK + rb] = vb.z; U[(kk2 + 3) * RBK + rb] = vb.w;
        }
      }
      if (k0 + 200 < 1000) {
        va = *(const float4*)(cell + (size_t)(R + ra) * 1000 + (k0 + 200) + ka * 4);
        if (t < 144)
          vb = *(const float4*)(cell + (size_t)(R + rb) * 1000 + (k0 + 200) + kb * 4);
      }
      __syncthreads();
#pragma unroll 8
      for (int k = 0; k < 200; ++k) {
        float4 h = *(const float4*)(U + k * RBK + r0);
        const float* wr = Wr1 + (size_t)(k0 + k) * 512 + f;
#pragma unroll
        for (int j = 0; j < 4; ++j) {
          float w = wr[j * 128];
          acc[0][j] = fmaf(h.x, w, acc[0][j]);
          acc[1][j] = fmaf(h.y, w, acc[1][j]);
          acc[2][j] = fmaf(h.z, w, acc[2][j]);
          acc[3][j] = fmaf(h.w, w, acc[3][j]);
        }
      }
    }
    __syncthreads();
#pragma unroll
    for (int j = 0; j < 4; ++j) {
      int ff = f + j * 128;
      float bb = br1[ff];
      float4 o;
      o.x = fmaxf(acc[0][j] + bb, 0.f); o.y = fmaxf(acc[1][j] + bb, 0.f);
      o.z = fmaxf(acc[2][j] + bb, 0.f); o.w = fmaxf(acc[3][j] + bb, 0.f);
      *(float4*)(U + ff * RBK + r0) = o;
    }
    __syncthreads();

    float a2[4][2];
#pragma unroll
    for (int i = 0; i < 4; ++i) { a2[i][0] = 0.f; a2[i][1] = 0.f; }
#pragma unroll 8
    for (int k = 0; k < 512; ++k) {
      float4 h = *(const float4*)(U + k * RBK + r0);
      const float* wr = Wr2 + (size_t)k * 256 + f;
#pragma unroll
      for (int j = 0; j < 2; ++j) {
        float w = wr[j * 128];
        a2[0][j] = fmaf(h.x, w, a2[0][j]);
        a2[1][j] = fmaf(h.y, w, a2[1][j]);
        a2[2][j] = fmaf(h.z, w, a2[2][j]);
        a2[3][j] = fmaf(h.w, w, a2[3][j]);
      }
    }
#pragma unroll
    for (int j = 0; j < 2; ++j) {
      int ff = f + j * 128;
      float bb = br2[ff];
      float4 o;
      o.x = fmaxf(a2[0][j] + bb, 0.f); o.y = fmaxf(a2[1][j] + bb, 0.f);
      o.z = fmaxf(a2[2][j] + bb, 0.f); o.w = fmaxf(a2[3][j] + bb, 0.f);
      *(float4*)(h2 + ff * RBK + r0) = o;
    }
    __syncthreads();

    float a3[4];
#pragma unroll
    for (int i = 0; i < 4; ++i) a3[i] = 0.f;
#pragma unroll 8
    for (int k = 0; k < 256; ++k) {
      float4 h = *(const float4*)(h2 + k * RBK + r0);
      float w = Wr3[(size_t)k * 128 + f];
      a3[0] = fmaf(h.x, w, a3[0]);
      a3[1] = fmaf(h.y, w, a3[1]);
      a3[2] = fmaf(h.z, w, a3[2]);
      a3[3] = fmaf(h.w, w, a3[3]);
    }
    {
      float bb = br3[f];
#pragma unroll
      for (int i = 0; i < 4; ++i)
        cout[(size_t)(R + r0 + i) * GOC + f] = a3[i] + bb;
    }
    return;
  }

  // ================= drug path =================
  short* Xb   = (short*)smem;             // [160][XBS] bf16, 12800 B
  short* Hb   = (short*)(smem + 12800);   // [32][HBS]  bf16, 10752 B
  float* As   = (float*)(smem + 23552);   // [32][HS]   fp32,  4608 B
  short* Asb  = (short*)(smem + 28160);   // [32][32]   bf16,  2048 B
  float* gbuf = (float*)(smem + 30208);   //                   1248 B
  float* deg  = (float*)(smem + 31456);   //                    128 B
  unsigned* gbufU = (unsigned*)gbuf;

  const int bid = blockIdx.x - NCELLB;
  const int gid = bid & (N_GRAPHSC - 1);
  const int drug = bid >> 13;
  const float* __restrict__ x = drug ? x2 : x1;
  const int* __restrict__ ei = drug ? ei2 : ei1;
  const int nbase = gid * NPG;

  if (t < NPG) deg[t] = 0.f;
  for (int i = t; i < NPG * HS; i += 256) As[i] = 0.f;
  for (int i = t; i < NPG * HBS / 2; i += 256) ((int*)Hb)[i] = 0;
  {
    int* xz = (int*)(Xb + FXD * XBS);     // rows [78,160) must stay zero
    for (int i = t; i < (160 - FXD) * XBS / 2; i += 256) xz[i] = 0;
  }
  for (int i = t; i < F3C; i += 256) gbufU[i] = 0u;
  const float* xg = x + (size_t)gid * (NPG * FXD);
  float4 xv[3];
#pragma unroll
  for (int j = 0; j < 3; ++j) {
    int idx = t + j * 256;
    if (idx < (NPG * FXD) / 4) xv[j] = ((const float4*)xg)[idx];
  }
  int s = 0, d = 0;
  if (t < EPG) {
    s = ei[(size_t)gid * EPG + t] - nbase;
    d = ei[(size_t)N_EDGESC + (size_t)gid * EPG + t] - nbase;
  }
#pragma unroll
  for (int j = 0; j < 3; ++j) {
    int idx = t + j * 256;
    if (idx < (NPG * FXD) / 4) {
      const float* vp = (const float*)&xv[j];
      int base = idx * 4;
#pragma unroll
      for (int jj = 0; jj < 4; ++jj) {
        int id2 = base + jj;
        int n = id2 / FXD;
        int k = id2 - n * FXD;
        Xb[k * XBS + n] = f2bf(vp[jj]);
      }
    }
  }
  __syncthreads();
  if (t < EPG) atomicAdd(&deg[s], 1.0f);
  __syncthreads();
  if (t < EPG) {
    float wgt = rsqrtf(deg[s] + 1.0f) * rsqrtf(deg[d] + 1.0f);
    atomicAdd(&As[d * HS + s], wgt);   // A[s][d]: msg d->s
  }
  if (t < NPG) atomicAdd(&As[t * HS + t], 1.0f / (deg[t] + 1.0f));
  __syncthreads();
  for (int i = t; i < NPG * NPG; i += 256) {
    int ss = i >> 5, dd = i & 31;
    Asb[ss * 32 + dd] = f2bf(As[dd * HS + ss]);
  }
  __syncthreads();

  agg_mfma<5>(Asb, Xb, Hb, t);
  __syncthreads();
  mm_mfma<3, 5, 96, FXD, false>(Hb, Wt1, b1, Xb, nullptr, t);
  __syncthreads();
  agg_mfma<5>(Asb, Xb, Hb, t);
  __syncthreads();
  mm_mfma<3, 10, 96, F2C, false>(Hb, Wt2, b2, Xb, nullptr, t);
  __syncthreads();
  agg_mfma<10>(Asb, Xb, Hb, t);
  __syncthreads();
  mm_mfma<5, 20, 160, F3C, true>(Hb, Wt3, b3, nullptr, gbufU, t);
  __syncthreads();

  const int p = drug * N_GRAPHSC + gid;
  for (int i = t; i < F3C; i += 256) pbuf[(size_t)p * F3C + i] = gbuf[i];
}

// ---------------------------------------------------------------------------
// ghead_mfma: the whole tail (gmlp 312->156->128 x2 drugs, normalize, head
// 384->512->128->1, sigmoid) on MFMA. 512 blocks x 16 samples, 256 threads.
// A-operands in LDS bf16 with row strides = 4 dwords mod 32 (2-way bank
// aliasing = free). ssq from fp32 pre-rounding values; scal/PReLU/Wo/sigmoid
// fp32. K-pads zeroed on both A (LDS cols) and B (pack_wt) sides.
// LDS overlay: U0[32][328]@0 (20992) | H1b[32][168]@20992 (10752) |
// Uxc[16][392]@31744 (12544) | Uh[16][520]@0 (16640, over dead U0) |
// ssq/scal/logit @44288. Total 44544 B.
__global__ __launch_bounds__(256, 2)
void ghead_mfma(const float* __restrict__ pbuf, const float* __restrict__ cbuf,
                const short* __restrict__ Wtg1, const float* __restrict__ bg1,
                const short* __restrict__ Wtg2, const float* __restrict__ bg2,
                const short* __restrict__ Wtf1, const float* __restrict__ bf1,
                const short* __restrict__ Wtf2, const float* __restrict__ bf2,
                const float* __restrict__ Wo, const float* __restrict__ bo,
                const float* __restrict__ pa, float* __restrict__ out) {
  __shared__ __align__(16) char smem[44544];
  short* U0   = (short*)smem;             // [32][328] gmlp A (both drugs)
  short* H1b  = (short*)(smem + 20992);   // [32][168] gmlp hidden
  short* Uxc  = (short*)(smem + 31744);   // [16][392] concat(g0,g1,c) bf16
  short* Uh   = (short*)smem;             // [16][520] head hidden (over U0)
  float* ssq  = (float*)(smem + 44288);   // [16]
  float* scal = (float*)(smem + 44352);   // [16]
  float* logit= (float*)(smem + 44416);   // [16]

  const int t = threadIdx.x;
  const int R = blockIdx.x * GM;
  const float aP = pa[0];
  const int w = t >> 6, L = t & 63, q = L >> 4;

  // ---- P0: zeros + stage pbuf -> U0 (bf16)
  if (t < GM) { ssq[t] = 0.f; logit[t] = 0.f; }
  for (int i = t; i < 128; i += 256) {          // U0 cols [312,320) = 0
    int r = i >> 2;
    ((int*)(U0 + r * 328 + 312))[i & 3] = 0;
  }
  if (t < 64) {                                 // H1b cols [156,160) = 0
    int r = t >> 1;
    ((int*)(H1b + r * 168 + 156))[t & 1] = 0;
  }
  for (int i = t; i < 32 * 78; i += 256) {
    int r = i / 78, c4 = i - r * 78;
    size_t srow = (r < GM) ? (size_t)(R + r)
                           : (size_t)(N_GRAPHSC + R + r - GM);
    float4 v = *(const float4*)(pbuf + srow * F3C + c4 * 4);
    short* dp = U0 + r * 328 + c4 * 4;
    dp[0] = f2bf(v.x); dp[1] = f2bf(v.y); dp[2] = f2bf(v.z); dp[3] = f2bf(v.w);
  }
  __syncthreads();

  // ---- c staging: Uxc[:, 256..383] + ssq contribution (fp32)
  for (int i = t; i < 512; i += 256) {
    int r = i >> 5, c4 = i & 31;
    float4 v = *(const float4*)(cbuf + (size_t)(R + r) * GOC + c4 * 4);
    atomicAdd(&ssq[r], v.x * v.x + v.y * v.y + v.z * v.z + v.w * v.w);
    short* dp = Uxc + r * 392 + 256 + c4 * 4;
    dp[0] = f2bf(v.x); dp[1] = f2bf(v.y); dp[2] = f2bf(v.z); dp[3] = f2bf(v.w);
  }

  // ---- G1: gmlp L1, M=32 (2 m-tiles), N=160, K=320
  {
    const int mt = w & 1;
    const int m = mt * 16 + (L & 15);
    short8v af[10];
#pragma unroll
    for (int s = 0; s < 10; ++s)
      af[s] = *(const short8v*)(U0 + m * 328 + s * 32 + q * 8);
    for (int nt = (w >> 1); nt < 10; nt += 2) {
      const int f = nt * 16 + (L & 15);
      float4v acc = {0.f, 0.f, 0.f, 0.f};
#pragma unroll
      for (int s = 0; s < 10; ++s) {
        short8v bf = *(const short8v*)(Wtg1 + (size_t)f * 320 + s * 32 + q * 8);
        acc = __builtin_amdgcn_mfma_f32_16x16x32_bf16(af[s], bf, acc, 0, 0, 0);
      }
      if (f < GHC) {
        float bb = bg1[f];
#pragma unroll
        for (int i = 0; i < 4; ++i) {
          float v = fmaxf(acc[i] + bb, 0.f);
          H1b[(mt * 16 + q * 4 + i) * 168 + f] = f2bf(v);
        }
      }
    }
  }
  __syncthreads();

  // ---- G2: gmlp L2, M=32, N=128, K=160 -> Uxc cols 0..255 + ssq
  {
    const int mt = w & 1;
    const int m = mt * 16 + (L & 15);
    short8v af[5];
#pragma unroll
    for (int s = 0; s < 5; ++s)
      af[s] = *(const short8v*)(H1b + m * 168 + s * 32 + q * 8);
    for (int nt = (w >> 1); nt < 8; nt += 2) {
      const int f = nt * 16 + (L & 15);
      float4v acc = {0.f, 0.f, 0.f, 0.f};
#pragma unroll
      for (int s = 0; s < 5; ++s) {
        short8v bf = *(const short8v*)(Wtg2 + (size_t)f * 160 + s * 32 + q * 8);
        acc = __builtin_amdgcn_mfma_f32_16x16x32_bf16(af[s], bf, acc, 0, 0, 0);
      }
      float bb = bg2[f];
#pragma unroll
      for (int i = 0; i < 4; ++i) {
        int row = mt * 16 + q * 4 + i;
        float v = acc[i] + bb;
        atomicAdd(&ssq[row & 15], v * v);
        int col = (row < GM) ? f : (GOC + f);
        Uxc[(row & 15) * 392 + col] = f2bf(v);
      }
    }
  }
  __syncthreads();

  if (t < GM) scal[t] = 1.0f / fmaxf(sqrtf(ssq[t]), 1e-12f);
  __syncthreads();

  // ---- H1: head L1, M=16 (1 m-tile, nt across all 4 waves), N=512, K=384
  {
    const int m = L & 15;
    short8v af[12];
#pragma unroll
    for (int s = 0; s < 12; ++s)
      af[s] = *(const short8v*)(Uxc + m * 392 + s * 32 + q * 8);
    for (int nt = w; nt < 32; nt += 4) {
      const int f = nt * 16 + (L & 15);
      float4v acc = {0.f, 0.f, 0.f, 0.f};
#pragma unroll
      for (int s = 0; s < 12; ++s) {
        short8v bf = *(const short8v*)(Wtf1 + (size_t)f * 384 + s * 32 + q * 8);
        acc = __builtin_amdgcn_mfma_f32_16x16x32_bf16(af[s], bf, acc, 0, 0, 0);
      }
      float bb = bf1[f];
#pragma unroll
      for (int i = 0; i < 4; ++i) {
        int row = q * 4 + i;
        float v = acc[i] * scal[row] + bb;
        v = v >= 0.f ? v : aP * v;
        Uh[row * 520 + f] = f2bf(v);
      }
    }
  }
  __syncthreads();

  // ---- H2: head L2, M=16, N=128, K=512; fold Wo dot into epilogue
  {
    const int m = L & 15;
    short8v af[16];
#pragma unroll
    for (int s = 0; s < 16; ++s)
      af[s] = *(const short8v*)(Uh + m * 520 + s * 32 + q * 8);
    float part[4] = {0.f, 0.f, 0.f, 0.f};
    for (int nt = w; nt < 8; nt += 4) {
      const int f = nt * 16 + (L & 15);
      float4v acc = {0.f, 0.f, 0.f, 0.f};
#pragma unroll
      for (int s = 0; s < 16; ++s) {
        short8v bf = *(const short8v*)(Wtf2 + (size_t)f * 512 + s * 32 + q * 8);
        acc = __builtin_amdgcn_mfma_f32_16x16x32_bf16(af[s], bf, acc, 0, 0, 0);
      }
      float bb = bf2[f];
      float wo = Wo[f];
#pragma unroll
      for (int i = 0; i < 4; ++i) {
        float v = acc[i] + bb;
        v = v >= 0.f ? v : aP * v;
        part[i] = fmaf(v, wo, part[i]);
      }
    }
#pragma unroll
    for (int i = 0; i < 4; ++i)
      atomicAdd(&logit[q * 4 + i], part[i]);
  }
  __syncthreads();

  if (t < GM)
    out[R + t] = 1.0f / (1.0f + expf(-(logit[t] + bo[0])));
}

// ---------------------------------------------------------------------------
extern "C" void kernel_launch(void* const* d_in, const int* in_sizes, int n_in,
                              void* d_out, int out_size, void* d_ws, size_t ws_size,
                              hipStream_t stream) {
  const float* x1  = (const float*)d_in[0];
  const int*   ei1 = (const int*)d_in[1];
  const float* x2  = (const float*)d_in[2];
  const int*   ei2 = (const int*)d_in[3];
  const float* cel = (const float*)d_in[4];
  const float* W1  = (const float*)d_in[7];
  const float* b1  = (const float*)d_in[8];
  const float* W2  = (const float*)d_in[9];
  const float* b2  = (const float*)d_in[10];
  const float* W3  = (const float*)d_in[11];
  const float* b3  = (const float*)d_in[12];
  const float* Wg1 = (const float*)d_in[13];
  const float* bg1 = (const float*)d_in[14];
  const float* Wg2 = (const float*)d_in[15];
  const float* bg2 = (const float*)d_in[16];
  const float* Wr1 = (const float*)d_in[17];
  const float* br1 = (const float*)d_in[18];
  const float* Wr2 = (const float*)d_in[19];
  const float* br2 = (const float*)d_in[20];
  const float* Wr3 = (const float*)d_in[21];
  const float* br3 = (const float*)d_in[22];
  const float* Wf1 = (const float*)d_in[23];
  const float* bf1 = (const float*)d_in[24];
  const float* Wf2 = (const float*)d_in[25];
  const float* bf2 = (const float*)d_in[26];
  const float* Wo  = (const float*)d_in[27];
  const float* bo  = (const float*)d_in[28];
  const float* pa  = (const float*)d_in[29];

  float* ws    = (float*)d_ws;
  // tail bf16 weight packs live in the (now unused) g1buf/g2buf region
  short* wtg1  = (short*)ws;                     // 160x320 = 51200
  short* wtg2  = wtg1 + 160 * 320;               // 128x160 = 20480
  short* wtf1  = wtg2 + 128 * 160;               // 512x384 = 196608
  short* wtf2  = wtf1 + 512 * 384;               // 128x512 = 65536  (total 333824 shorts << 2*N*GOC floats)
  float* cbuf  = ws + (size_t)2 * N_GRAPHSC * GOC;
  short* wt1   = (short*)(ws + (size_t)3 * N_GRAPHSC * GOC);  // 80x96
  short* wt2   = wt1 + 80 * 96;                               // 160x96
  short* wt3   = wt2 + 160 * 96;                               // 320x160
  float* pbuf  = ws + (size_t)3 * N_GRAPHSC * GOC + 37120;     // 16384x312
  float* outp  = (float*)d_out;

  pack_wt<<<dim3((80 * 96 + 255) / 256), dim3(256), 0, stream>>>(W1, wt1, FXD, FXD, 96, 80);
  pack_wt<<<dim3((160 * 96 + 255) / 256), dim3(256), 0, stream>>>(W2, wt2, FXD, F2C, 96, 160);
  pack_wt<<<dim3((320 * 160 + 255) / 256), dim3(256), 0, stream>>>(W3, wt3, F2C, F3C, 160, 320);
  pack_wt<<<dim3(200), dim3(256), 0, stream>>>(Wg1, wtg1, F3C, GHC, 320, 160);
  pack_wt<<<dim3(80),  dim3(256), 0, stream>>>(Wg2, wtg2, GHC, GOC, 160, 128);
  pack_wt<<<dim3(768), dim3(256), 0, stream>>>(Wf1, wtf1, 3 * GOC, 512, 384, 512);
  pack_wt<<<dim3(256), dim3(256), 0, stream>>>(Wf2, wtf2, 512, GOC, 512, 128);

  fused_kernel<<<dim3(NCELLB + 2 * N_GRAPHSC), dim3(256), 0, stream>>>(
      x1, ei1, x2, ei2, wt1, b1, wt2, b2, wt3, b3, pbuf,
      cel, Wr1, br1, Wr2, br2, Wr3, br3, cbuf);
  ghead_mfma<<<dim3(N_GRAPHSC / GM), dim3(256), 0, stream>>>(
      pbuf, cbuf, wtg1, bg1, wtg2, bg2, wtf1, bf1, wtf2, bf2, Wo, bo, pa, outp);
}